// Round 19
// baseline (246.897 us; speedup 1.0000x reference)
//
#include <hip/hip_runtime.h>

// TransformerBlock on MI355X: LN1 -> QKV -> causal MHA -> O-proj+res -> LN2 -> FFN+res
// R19: gemm128 REVERTED to R17's 2-phase BK=64 (R18's 8-phase gemm128 regressed:
// 8-MFMA phases too short). QKV moved onto the R17-verified 8-phase gemm256
// (grid 16x12, EPI_QKV epilogue added there). O-proj on 2-phase gemm128.
// FFN1/FFN2 on 8-phase gemm256, attention/combines/pack frozen from R17.

typedef __bf16 bf16_t;
typedef __attribute__((ext_vector_type(8))) __bf16 bf16x8;
typedef __attribute__((ext_vector_type(4))) __bf16 bf16x4;
typedef __attribute__((ext_vector_type(4))) float f32x4;

#define B_DIM 2
#define S_DIM 2048
#define E_DIM 1024
#define H_DIM 16
#define DH_DIM 64

#define GLD16(gp, lp) __builtin_amdgcn_global_load_lds( \
    (const __attribute__((address_space(1))) void*)(gp), \
    (__attribute__((address_space(3))) void*)(lp), 16, 0, 0)

// fold E^-0.5 (=1/32) and log2(e) into Q so softmax can use exp2 directly
#define Q_SCALE 0.0450842120f

// ---------------- LayerNorm: fp32 in -> bf16 out (one block per row) -------------
__global__ __launch_bounds__(256) void ln_kernel(
    const float* __restrict__ x, const float* __restrict__ g,
    const float* __restrict__ bv, bf16_t* __restrict__ out)
{
  const int row = blockIdx.x;
  const int t = threadIdx.x;
  const float* xr = x + (size_t)row * E_DIM;
  float4 v = *(const float4*)&xr[t * 4];
  float s  = v.x + v.y + v.z + v.w;
  float s2 = v.x*v.x + v.y*v.y + v.z*v.z + v.w*v.w;
#pragma unroll
  for (int m = 1; m < 64; m <<= 1) {
    s  += __shfl_xor(s,  m, 64);
    s2 += __shfl_xor(s2, m, 64);
  }
  __shared__ float red[8];
  const int wid = t >> 6, lane = t & 63;
  if (lane == 0) { red[wid] = s; red[4 + wid] = s2; }
  __syncthreads();
  s  = red[0] + red[1] + red[2] + red[3];
  s2 = red[4] + red[5] + red[6] + red[7];
  const float mu  = s * (1.f / E_DIM);
  const float var = s2 * (1.f / E_DIM) - mu * mu;
  const float rs  = rsqrtf(var + 1e-5f);
  float4 gg = *(const float4*)&g[t * 4];
  float4 bb = *(const float4*)&bv[t * 4];
  bf16x4 o;
  o[0] = (bf16_t)((v.x - mu) * rs * gg.x + bb.x);
  o[1] = (bf16_t)((v.y - mu) * rs * gg.y + bb.y);
  o[2] = (bf16_t)((v.z - mu) * rs * gg.z + bb.z);
  o[3] = (bf16_t)((v.w - mu) * rs * gg.w + bb.w);
  *(bf16x4*)&out[(size_t)row * E_DIM + t * 4] = o;
}

// ---- O-proj split-K combine (2 bf16 partials) + bias + residual -> xmid, LN2 -> h2
__global__ __launch_bounds__(256) void reduce2_ln(
    const bf16_t* __restrict__ p0, const bf16_t* __restrict__ p1,
    const float* __restrict__ bo, const float* __restrict__ x,
    const float* __restrict__ g, const float* __restrict__ bv,
    float* __restrict__ xmid, bf16_t* __restrict__ h2)
{
  const int row = blockIdx.x;
  const int t = threadIdx.x;
  const size_t off = (size_t)row * E_DIM + t * 4;
  bf16x4 a = *(const bf16x4*)&p0[off];
  bf16x4 b4 = *(const bf16x4*)&p1[off];
  float4 xr = *(const float4*)&x[off];
  float4 bo4 = *(const float4*)&bo[t * 4];
  float4 v;
  v.x = (float)a[0] + (float)b4[0] + xr.x + bo4.x;
  v.y = (float)a[1] + (float)b4[1] + xr.y + bo4.y;
  v.z = (float)a[2] + (float)b4[2] + xr.z + bo4.z;
  v.w = (float)a[3] + (float)b4[3] + xr.w + bo4.w;
  *(float4*)&xmid[off] = v;
  float s  = v.x + v.y + v.z + v.w;
  float s2 = v.x*v.x + v.y*v.y + v.z*v.z + v.w*v.w;
#pragma unroll
  for (int m = 1; m < 64; m <<= 1) {
    s  += __shfl_xor(s,  m, 64);
    s2 += __shfl_xor(s2, m, 64);
  }
  __shared__ float red[8];
  const int wid = t >> 6, lane = t & 63;
  if (lane == 0) { red[wid] = s; red[4 + wid] = s2; }
  __syncthreads();
  s  = red[0] + red[1] + red[2] + red[3];
  s2 = red[4] + red[5] + red[6] + red[7];
  const float mu  = s * (1.f / E_DIM);
  const float var = s2 * (1.f / E_DIM) - mu * mu;
  const float rs  = rsqrtf(var + 1e-5f);
  float4 gg = *(const float4*)&g[t * 4];
  float4 bb = *(const float4*)&bv[t * 4];
  bf16x4 o;
  o[0] = (bf16_t)((v.x - mu) * rs * gg.x + bb.x);
  o[1] = (bf16_t)((v.y - mu) * rs * gg.y + bb.y);
  o[2] = (bf16_t)((v.z - mu) * rs * gg.z + bb.z);
  o[3] = (bf16_t)((v.w - mu) * rs * gg.w + bb.w);
  *(bf16x4*)&h2[off] = o;
}

// ---- FFN2 split-K combine (4 bf16 partials) + bias + residual -> d_out (f32) -----
__global__ __launch_bounds__(256) void reduce4(
    const bf16_t* __restrict__ p0, const bf16_t* __restrict__ p1,
    const bf16_t* __restrict__ p2, const bf16_t* __restrict__ p3,
    const float* __restrict__ b2, const float* __restrict__ xm,
    float* __restrict__ out)
{
  const int row = blockIdx.x;
  const int t = threadIdx.x;
  const size_t off = (size_t)row * E_DIM + t * 4;
  bf16x4 a0 = *(const bf16x4*)&p0[off];
  bf16x4 a1 = *(const bf16x4*)&p1[off];
  bf16x4 a2 = *(const bf16x4*)&p2[off];
  bf16x4 a3 = *(const bf16x4*)&p3[off];
  float4 xr = *(const float4*)&xm[off];
  float4 bb = *(const float4*)&b2[t * 4];
  float4 o;
  o.x = (float)a0[0] + (float)a1[0] + (float)a2[0] + (float)a3[0] + xr.x + bb.x;
  o.y = (float)a0[1] + (float)a1[1] + (float)a2[1] + (float)a3[1] + xr.y + bb.y;
  o.z = (float)a0[2] + (float)a1[2] + (float)a2[2] + (float)a3[2] + xr.z + bb.z;
  o.w = (float)a0[3] + (float)a1[3] + (float)a2[3] + (float)a3[3] + xr.w + bb.w;
  *(float4*)&out[off] = o;
}

// -------- fused weight pack: all four transposes in ONE launch ---------------------
__global__ __launch_bounds__(256) void pack_weights(
    const float* __restrict__ Wq, const float* __restrict__ Wk,
    const float* __restrict__ Wv, bf16_t* __restrict__ WqkvT,
    const float* __restrict__ Wo, bf16_t* __restrict__ WoT,
    const float* __restrict__ W1, bf16_t* __restrict__ W1T,
    const float* __restrict__ W2, bf16_t* __restrict__ W2T)
{
  __shared__ float tile[64][65];
  const int bid = blockIdx.x;
  const int t = threadIdx.x;
  const int rr = t >> 2;

  if (bid < 768) {
    const int byq = bid >> 4, bxq = bid & 15;
    const int m = byq >> 4, h = byq & 15;
    const float* src = (m == 0 ? Wq : (m == 1 ? Wk : Wv)) + (size_t)h * E_DIM * DH_DIM;
    const int e0 = bxq * 64;
#pragma unroll
    for (int u = 0; u < 4; u++) {
      const int cc = (t & 3) * 4 + u * 16;
      float4 f = *(const float4*)&src[(size_t)(e0 + rr) * DH_DIM + cc];
      tile[rr][cc + 0] = f.x; tile[rr][cc + 1] = f.y;
      tile[rr][cc + 2] = f.z; tile[rr][cc + 3] = f.w;
    }
    __syncthreads();
    const int oc = t >> 2;  // d index 0..63
    const size_t drow = (size_t)(m * 1024 + h * 64 + oc) * E_DIM;
#pragma unroll
    for (int u = 0; u < 4; u++) {
      const int orr = (t & 3) * 4 + u * 16;
      bf16x4 w;
      w[0] = (bf16_t)tile[orr + 0][oc];
      w[1] = (bf16_t)tile[orr + 1][oc];
      w[2] = (bf16_t)tile[orr + 2][oc];
      w[3] = (bf16_t)tile[orr + 3][oc];
      *(bf16x4*)&WqkvT[drow + e0 + orr] = w;
    }
    return;
  }

  const float* src; bf16_t* dst; int R, C, bx, by;
  if (bid < 1024)      { const int r = bid - 768;  src = Wo; dst = WoT; R = 1024; C = 1024; bx = r & 15; by = r >> 4; }
  else if (bid < 2048) { const int r = bid - 1024; src = W1; dst = W1T; R = 1024; C = 4096; bx = r & 63; by = r >> 6; }
  else                 { const int r = bid - 2048; src = W2; dst = W2T; R = 4096; C = 1024; bx = r & 15; by = r >> 4; }
  const int c0 = bx * 64, r0 = by * 64;
#pragma unroll
  for (int u = 0; u < 4; u++) {
    const int cc = (t & 3) * 4 + u * 16;
    float4 f = *(const float4*)&src[(size_t)(r0 + rr) * C + c0 + cc];
    tile[rr][cc + 0] = f.x; tile[rr][cc + 1] = f.y;
    tile[rr][cc + 2] = f.z; tile[rr][cc + 3] = f.w;
  }
  __syncthreads();
  const int oc = t >> 2;
#pragma unroll
  for (int u = 0; u < 4; u++) {
    const int orr = (t & 3) * 4 + u * 16;
    bf16x4 w;
    w[0] = (bf16_t)tile[orr + 0][oc];
    w[1] = (bf16_t)tile[orr + 1][oc];
    w[2] = (bf16_t)tile[orr + 2][oc];
    w[3] = (bf16_t)tile[orr + 3][oc];
    *(bf16x4*)&dst[(size_t)(c0 + oc) * R + r0 + orr] = w;
  }
}

constexpr int EPI_QKV = 0, EPI_BIAS_RELU = 2, EPI_PART_F32 = 3, EPI_PART_B16 = 4;

// XCD-region swizzle (all GEMMs): lin = by*gx+bx; xcd = lin&7; k = lin>>3.
// 8 regions of RM x RN blocks; within region m-minor (B-panel reuse, A panels in L2).

// ------------- 128x128-tile MFMA GEMM, BK=64, 2-phase pipeline (R17 form) ----------
// LDS rows 128B: global (row r, 8-elem group u of 8) at byte r*128 + (u^(r&7))*16.
template <int EPI>
__global__ __launch_bounds__(256) void gemm128_kernel(
    const bf16_t* __restrict__ A, const bf16_t* __restrict__ Bt,
    int M, int N, int Kst, int Klen, int RM, int RN,
    const float* __restrict__ bias,
    float* __restrict__ outF, bf16_t* __restrict__ outB,
    bf16_t* __restrict__ qo, bf16_t* __restrict__ ko, bf16_t* __restrict__ vo)
{
  __shared__ bf16_t As[2][128 * 64];   // 32KB
  __shared__ bf16_t Bs[2][128 * 64];   // 32KB
  const int gx = gridDim.x;
  const int lin = blockIdx.y * gx + blockIdx.x;
  const int xcd = lin & 7, kb = lin >> 3;
  const int nregx = gx / RM;
  const int rx = xcd % nregx, ry = xcd / nregx;
  const int m0 = (rx * RM + kb % RM) * 128;
  const int n0 = (ry * RN + kb / RM) * 128;
  const int sp = blockIdx.z;
  A  += (size_t)sp * Klen;
  Bt += (size_t)sp * Klen;

  const int tid = threadIdx.x, lane = tid & 63, wid = tid >> 6;
  const int wr = wid >> 1, wc = wid & 1;
  const int lr = lane & 15, lg = lane >> 4;
  const int l7 = lr & 7;
  const int sl[2] = { (lg ^ l7) * 16, ((4 | lg) ^ l7) * 16 };  // kk = 0, 1
  const int rbA = (wr * 64 + lr) * 128;   // + i*2048
  const int rbB = (wc * 64 + lr) * 128;   // + j*2048

  auto stage = [&](int kt, int buf) {
#pragma unroll
    for (int q = 0; q < 4; q++) {
      const int L = q * 256 + tid;
      const int row = L >> 3;
      const int u = (L & 7) ^ (row & 7);
      char* la = (char*)&As[buf][0] + (size_t)(q * 256 + wid * 64) * 16;
      char* lb = (char*)&Bs[buf][0] + (size_t)(q * 256 + wid * 64) * 16;
      GLD16(A  + (size_t)(m0 + row) * Kst + kt * 64 + u * 8, la);
      GLD16(Bt + (size_t)(n0 + row) * Kst + kt * 64 + u * 8, lb);
    }
  };

  const f32x4 z4 = {0.f, 0.f, 0.f, 0.f};
  f32x4 acc[4][4];
#pragma unroll
  for (int i = 0; i < 4; i++)
#pragma unroll
    for (int j = 0; j < 4; j++) acc[i][j] = z4;

  const int NT = Klen / 64;
  stage(0, 0);
  for (int T = 0; T < NT; ++T) {
    const int b = T & 1;
    asm volatile("s_waitcnt vmcnt(0)" ::: "memory");  // own stage(T) landed
    __builtin_amdgcn_s_barrier();                     // everyone's stage(T) visible
    if (T + 1 < NT) stage(T + 1, b ^ 1);              // flies under compute T
    __builtin_amdgcn_sched_barrier(0);

    bf16x8 bfr[2][4];
#pragma unroll
    for (int kk = 0; kk < 2; kk++)
#pragma unroll
      for (int j = 0; j < 4; j++)
        bfr[kk][j] = *(const bf16x8*)((const char*)&Bs[b][0] + rbB + j * 2048 + sl[kk]);
    __builtin_amdgcn_s_setprio(1);
#pragma unroll
    for (int i = 0; i < 4; i++) {
#pragma unroll
      for (int kk = 0; kk < 2; kk++) {
        bf16x8 af = *(const bf16x8*)((const char*)&As[b][0] + rbA + i * 2048 + sl[kk]);
#pragma unroll
        for (int j = 0; j < 4; j++)
          acc[i][j] = __builtin_amdgcn_mfma_f32_16x16x32_bf16(af, bfr[kk][j], acc[i][j], 0, 0, 0);
      }
    }
    __builtin_amdgcn_s_setprio(0);
  }

#pragma unroll
  for (int i = 0; i < 4; i++) {
#pragma unroll
    for (int j = 0; j < 4; j++) {
#pragma unroll
      for (int r = 0; r < 4; r++) {
        const int m = m0 + wr * 64 + i * 16 + lg * 4 + r;
        const int n = n0 + wc * 64 + j * 16 + lr;
        const float val = acc[i][j][r];
        if constexpr (EPI == EPI_QKV) {
          const int tsel = n >> 10, h = (n >> 6) & 15, d = n & 63;
          const int b_ = m >> 11, s_ = m & 2047;
          if (tsel == 0)
            qo[((size_t)((b_ * H_DIM + h) * S_DIM + s_)) * DH_DIM + d] = (bf16_t)(val * Q_SCALE);
          else if (tsel == 1)
            ko[((size_t)((b_ * H_DIM + h) * S_DIM + s_)) * DH_DIM + d] = (bf16_t)val;
          else  // V stored transposed: [b,h,d,s]
            vo[((size_t)((b_ * H_DIM + h) * DH_DIM + d)) * S_DIM + s_] = (bf16_t)val;
        } else if constexpr (EPI == EPI_BIAS_RELU) {
          const float u = val + bias[n];
          outB[(size_t)m * N + n] = (bf16_t)(u > 0.f ? u : 0.f);
        } else if constexpr (EPI == EPI_PART_F32) {
          outF[(size_t)sp * M * N + (size_t)m * N + n] = val;
        } else {
          bf16_t* o = sp == 0 ? outB : sp == 1 ? qo : sp == 2 ? ko : vo;
          o[(size_t)m * N + n] = (bf16_t)val;
        }
      }
    }
  }
}

// ------------- 256x256-tile MFMA GEMM, BK=64, 8-phase counted-vmcnt (R17) ----------
// LDS [2 buf][2 k-half] per matrix; paired-row swizzle per half. Now also hosts
// the QKV epilogue (pure function of computed m,n,val).
template <int EPI>
__global__ __launch_bounds__(512) void gemm256_kernel(
    const bf16_t* __restrict__ A, const bf16_t* __restrict__ Bt,
    int M, int N, int Kst, int Klen, int RM, int RN,
    const float* __restrict__ bias,
    float* __restrict__ outF, bf16_t* __restrict__ outB,
    bf16_t* __restrict__ qo, bf16_t* __restrict__ ko, bf16_t* __restrict__ vo)
{
  __shared__ bf16_t As[2][2][128 * 64];   // [buf][kh] 16KB each -> 64KB
  __shared__ bf16_t Bs[2][2][128 * 64];   // 64KB
  const int gx = gridDim.x;
  const int lin = blockIdx.y * gx + blockIdx.x;
  const int xcd = lin & 7, kb = lin >> 3;
  const int nregx = gx / RM;
  const int rx = xcd % nregx, ry = xcd / nregx;
  const int m0 = (rx * RM + kb % RM) * 256;
  const int n0 = (ry * RN + kb / RM) * 256;
  const int sp = blockIdx.z;
  A  += (size_t)sp * Klen;
  Bt += (size_t)sp * Klen;

  const int tid = threadIdx.x, lane = tid & 63, wid = tid >> 6;
  const int wm = wid >> 2, wn = wid & 3;
  const int lr = lane & 15, lg = lane >> 4;
  const int sl16 = (((lr & 1) * 4 + lg) ^ ((lr >> 1) & 7)) * 16;  // lane-constant
  const int rbA = (wm * 64 + (lr >> 1)) * 128 + sl16;   // + i*1024 within As[buf][kh]
  const int rbB = (wn * 32 + (lr >> 1)) * 128 + sl16;   // + j*1024 within Bs[buf][kh]

  auto stageU = [&](int kt, int kh, int matB) {
    const int buf = kt & 1;
#pragma unroll
    for (int p = 0; p < 2; p++) {
      const int L = p * 512 + tid;
      const int row2 = L >> 3;
      const int s = (L & 7) ^ (row2 & 7);
      const int r = row2 * 2 + (s >> 2);
      const int u = s & 3;
      char* lds = (char*)(matB ? &Bs[buf][kh][0] : &As[buf][kh][0])
                + (size_t)(p * 512 + wid * 64) * 16;
      const bf16_t* gp = (matB ? Bt + (size_t)(n0 + r) * Kst
                               : A  + (size_t)(m0 + r) * Kst)
                       + kt * 64 + kh * 32 + u * 8;
      GLD16(gp, lds);
    }
  };

  const f32x4 z4 = {0.f, 0.f, 0.f, 0.f};
  f32x4 acc[8][4];
#pragma unroll
  for (int i = 0; i < 8; i++)
#pragma unroll
    for (int j = 0; j < 4; j++) acc[i][j] = z4;

  const int NT = Klen / 64;
  stageU(0, 0, 0); stageU(0, 0, 1); stageU(0, 1, 0); stageU(0, 1, 1);
  asm volatile("s_waitcnt vmcnt(4)" ::: "memory");
  __builtin_amdgcn_s_barrier();
  __builtin_amdgcn_sched_barrier(0);

  for (int TT = 0; TT < NT; ++TT) {
    const int buf = TT & 1;
    bf16x8 bfr[4];
#pragma unroll
    for (int q = 0; q < 4; q++) {
      const int kh = q >> 1, mh = q & 1;
      if ((q & 1) == 0) {
#pragma unroll
        for (int j = 0; j < 4; j++)
          bfr[j] = *(const bf16x8*)((const char*)&Bs[buf][kh][0] + rbB + j * 1024);
      }
      bf16x8 af[4];
#pragma unroll
      for (int ii = 0; ii < 4; ii++)
        af[ii] = *(const bf16x8*)((const char*)&As[buf][kh][0] + rbA + (mh * 4 + ii) * 1024);
      if (TT + 1 < NT) stageU(TT + 1, q >> 1, q & 1);
      __builtin_amdgcn_s_setprio(1);
#pragma unroll
      for (int ii = 0; ii < 4; ii++)
#pragma unroll
        for (int j = 0; j < 4; j++)
          acc[mh * 4 + ii][j] =
              __builtin_amdgcn_mfma_f32_16x16x32_bf16(af[ii], bfr[j], acc[mh * 4 + ii][j], 0, 0, 0);
      __builtin_amdgcn_s_setprio(0);
      if (q & 1) {
        __builtin_amdgcn_sched_barrier(0);
        if (TT + 1 < NT) asm volatile("s_waitcnt vmcnt(4)" ::: "memory");
        else if (q == 1) asm volatile("s_waitcnt vmcnt(0)" ::: "memory");
      }
      __builtin_amdgcn_s_barrier();
      __builtin_amdgcn_sched_barrier(0);
    }
  }

#pragma unroll
  for (int i = 0; i < 8; i++) {
#pragma unroll
    for (int j = 0; j < 4; j++) {
#pragma unroll
      for (int r = 0; r < 4; r++) {
        const int m = m0 + wm * 128 + i * 16 + lg * 4 + r;
        const int n = n0 + wn * 64 + j * 16 + lr;
        const float val = acc[i][j][r];
        if constexpr (EPI == EPI_QKV) {
          const int tsel = n >> 10, h = (n >> 6) & 15, d = n & 63;
          const int b_ = m >> 11, s_ = m & 2047;
          if (tsel == 0)
            qo[((size_t)((b_ * H_DIM + h) * S_DIM + s_)) * DH_DIM + d] = (bf16_t)(val * Q_SCALE);
          else if (tsel == 1)
            ko[((size_t)((b_ * H_DIM + h) * S_DIM + s_)) * DH_DIM + d] = (bf16_t)val;
          else  // V stored transposed: [b,h,d,s]
            vo[((size_t)((b_ * H_DIM + h) * DH_DIM + d)) * S_DIM + s_] = (bf16_t)val;
        } else if constexpr (EPI == EPI_BIAS_RELU) {
          const float u = val + bias[n];
          outB[(size_t)m * N + n] = (bf16_t)(u > 0.f ? u : 0.f);
        } else if constexpr (EPI == EPI_PART_F32) {
          outF[(size_t)sp * M * N + (size_t)m * N + n] = val;
        } else if constexpr (EPI == EPI_PART_B16) {
          bf16_t* o = sp == 0 ? outB : sp == 1 ? qo : sp == 2 ? ko : vo;
          o[(size_t)m * N + n] = (bf16_t)val;
        }
      }
    }
  }
}

// ---------------- causal flash attention: 128 q-rows/block, uniform KV pieces ------
__global__ __launch_bounds__(256) void attn_kernel(
    const bf16_t* __restrict__ Q, const bf16_t* __restrict__ K,
    const bf16_t* __restrict__ Vt, bf16_t* __restrict__ O,
    bf16_t* __restrict__ Opart, float* __restrict__ mpart, float* __restrict__ lpart)
{
  __shared__ bf16_t Ks[2][64 * 64];      // [t][d], 16B slot ^= (t&7)
  __shared__ bf16_t Vs[2][64 * 64];      // [d][t], 16B slot ^= (d&7)
  __shared__ bf16_t Ps[4][2][16 * 64];   // per-wave, per-sub [q][t], slot ^= (q&7)

  const int nwg = 51 * gridDim.y;
  int id = blockIdx.y * 51 + blockIdx.x;
  id = (id & 7) * (nwg >> 3) + (id >> 3);
  const int bx = id % 51, bh = id / 51;

  int g = 0;
  while (3 * (g + 1) * (g + 2) / 2 <= bx) g++;      // <=5 iterations
  const int rr_ = bx - 3 * g * (g + 1) / 2;
  const int q2 = 3 * g + rr_ / (g + 1);
  const int sp = rr_ % (g + 1);
  const int ns = g + 1;
  const int n2 = 2 * q2 + 2;
  const int lo = 6 * sp;
  const int hi = (6 * sp + 6 < n2) ? 6 * sp + 6 : n2;

  const int tid = threadIdx.x;
  const int wid = tid >> 6, lane = tid & 63;
  const int lr = lane & 15, lg = lane >> 4;
  const int q0w = q2 * 128 + wid * 32;   // wave's 32 q rows; subs at +0, +16

  const bf16_t* Qp = Q  + (size_t)bh * S_DIM * DH_DIM;
  const bf16_t* Kp = K  + (size_t)bh * S_DIM * DH_DIM;
  const bf16_t* Vp = Vt + (size_t)bh * DH_DIM * S_DIM;  // [d][s]

  bf16x8 bq0[2], bq1[2];
#pragma unroll
  for (int c = 0; c < 2; c++) {
    bq0[c] = *(const bf16x8*)&Qp[(size_t)(q0w + lr) * DH_DIM + c * 32 + lg * 8];
    bq1[c] = *(const bf16x8*)&Qp[(size_t)(q0w + 16 + lr) * DH_DIM + c * 32 + lg * 8];
  }

  const f32x4 z4 = {0.f, 0.f, 0.f, 0.f};
  f32x4 Ot0[4], Ot1[4];   // O^T: Ot[dt][r] = O[q][d = dt*16 + lg*4 + r]
#pragma unroll
  for (int dt = 0; dt < 4; dt++) { Ot0[dt] = z4; Ot1[dt] = z4; }
  float mrow0 = -1e30f, lrow0 = 0.f;   // per-lane state, q = q0w + lr
  float mrow1 = -1e30f, lrow1 = 0.f;   // q = q0w + 16 + lr

  const int ktr = wid * 8 + (lane >> 3);
  const int ksc = lane & 7;

  auto stageKV = [&](int t0, int buf) {
#pragma unroll
    for (int p = 0; p < 2; p++) {
      const int tr = p * 32 + ktr;
      GLD16(Kp + (size_t)(t0 + tr) * DH_DIM + (ksc ^ (tr & 7)) * 8,
            &Ks[buf][(p * 32 + wid * 8) * 64]);
      GLD16(Vp + (size_t)tr * S_DIM + t0 + (ksc ^ (tr & 7)) * 8,
            &Vs[buf][(p * 32 + wid * 8) * 64]);
    }
  };

  stageKV(lo * 64, 0);

  for (int tc = lo; tc < hi; ++tc) {
    const int cur = (tc - lo) & 1;
    __syncthreads();                       // drains stageKV(tc); prev buf free
    if (tc + 1 < hi) stageKV((tc + 1) * 64, cur ^ 1);

    const int t0 = tc * 64;
    f32x4 s0[4], s1[4];
    __builtin_amdgcn_s_setprio(1);
#pragma unroll
    for (int j = 0; j < 4; j++) {
      f32x4 a = z4, b = z4;
      const int t = j * 16 + lr;
#pragma unroll
      for (int c = 0; c < 2; c++) {
        const int kbyte = t * 128 + (((c * 4 + lg) * 16) ^ ((t & 7) << 4));
        bf16x8 ak = *(const bf16x8*)((const char*)&Ks[cur][0] + kbyte);
        a = __builtin_amdgcn_mfma_f32_16x16x32_bf16(ak, bq0[c], a, 0, 0, 0);
        b = __builtin_amdgcn_mfma_f32_16x16x32_bf16(ak, bq1[c], b, 0, 0, 0);
      }
      s0[j] = a; s1[j] = b;
    }
    __builtin_amdgcn_s_setprio(0);
    if (tc >= 2 * q2) {   // chunks overlapping the block's causal diagonal
#pragma unroll
      for (int j = 0; j < 4; j++)
#pragma unroll
        for (int r = 0; r < 4; r++) {
          const int tg = t0 + j * 16 + lg * 4 + r;
          if (tg > q0w + lr)      s0[j][r] = -1e30f;
          if (tg > q0w + 16 + lr) s1[j][r] = -1e30f;
        }
    }
    // ---- softmax sub0 ----
    {
      float mj[4];
#pragma unroll
      for (int j = 0; j < 4; j++)
        mj[j] = fmaxf(fmaxf(s0[j][0], s0[j][1]), fmaxf(s0[j][2], s0[j][3]));
      float tmax = fmaxf(fmaxf(mj[0], mj[1]), fmaxf(mj[2], mj[3]));
      tmax = fmaxf(tmax, __shfl_xor(tmax, 16, 64));
      tmax = fmaxf(tmax, __shfl_xor(tmax, 32, 64));
      if (!__all(tmax <= mrow0 + 8.f)) {
        const float mnew = fmaxf(mrow0, tmax);
        const float fsc = __builtin_exp2f(mrow0 - mnew);
        mrow0 = mnew; lrow0 *= fsc;
#pragma unroll
        for (int dt = 0; dt < 4; dt++)
#pragma unroll
          for (int r = 0; r < 4; r++) Ot0[dt][r] *= fsc;
      }
      float sj[4];
#pragma unroll
      for (int j = 0; j < 4; j++) {
#pragma unroll
        for (int r = 0; r < 4; r++) s0[j][r] = __builtin_exp2f(s0[j][r] - mrow0);
        sj[j] = (s0[j][0] + s0[j][1]) + (s0[j][2] + s0[j][3]);
      }
      float tsum = (sj[0] + sj[1]) + (sj[2] + sj[3]);
      tsum += __shfl_xor(tsum, 16, 64);
      tsum += __shfl_xor(tsum, 32, 64);
      lrow0 += tsum;
#pragma unroll
      for (int j = 0; j < 4; j++) {
        bf16x4 w;
#pragma unroll
        for (int r = 0; r < 4; r++) w[r] = (bf16_t)s0[j][r];
        const int pbyte = lr * 128 + ((j * 32 + lg * 8) ^ ((lr & 7) << 4));
        *(bf16x4*)((char*)&Ps[wid][0][0] + pbyte) = w;
      }
    }
    // ---- softmax sub1 ----
    {
      float mj[4];
#pragma unroll
      for (int j = 0; j < 4; j++)
        mj[j] = fmaxf(fmaxf(s1[j][0], s1[j][1]), fmaxf(s1[j][2], s1[j][3]));
      float tmax = fmaxf(fmaxf(mj[0], mj[1]), fmaxf(mj[2], mj[3]));
      tmax = fmaxf(tmax, __shfl_xor(tmax, 16, 64));
      tmax = fmaxf(tmax, __shfl_xor(tmax, 32, 64));
      if (!__all(tmax <= mrow1 + 8.f)) {
        const float mnew = fmaxf(mrow1, tmax);
        const float fsc = __builtin_exp2f(mrow1 - mnew);
        mrow1 = mnew; lrow1 *= fsc;
#pragma unroll
        for (int dt = 0; dt < 4; dt++)
#pragma unroll
          for (int r = 0; r < 4; r++) Ot1[dt][r] *= fsc;
      }
      float sj[4];
#pragma unroll
      for (int j = 0; j < 4; j++) {
#pragma unroll
        for (int r = 0; r < 4; r++) s1[j][r] = __builtin_exp2f(s1[j][r] - mrow1);
        sj[j] = (s1[j][0] + s1[j][1]) + (s1[j][2] + s1[j][3]);
      }
      float tsum = (sj[0] + sj[1]) + (sj[2] + sj[3]);
      tsum += __shfl_xor(tsum, 16, 64);
      tsum += __shfl_xor(tsum, 32, 64);
      lrow1 += tsum;
#pragma unroll
      for (int j = 0; j < 4; j++) {
        bf16x4 w;
#pragma unroll
        for (int r = 0; r < 4; r++) w[r] = (bf16_t)s1[j][r];
        const int pbyte = lr * 128 + ((j * 32 + lg * 8) ^ ((lr & 7) << 4));
        *(bf16x4*)((char*)&Ps[wid][1][0] + pbyte) = w;
      }
    }

    // PV swapped, V-fragments shared across subs: Ot = mfma(bv, pa)
    __builtin_amdgcn_s_setprio(1);
#pragma unroll
    for (int c = 0; c < 2; c++) {
      const int abyte = lr * 128 + ((c * 64 + lg * 16) ^ ((lr & 7) << 4));
      bf16x8 pa0 = *(const bf16x8*)((const char*)&Ps[wid][0][0] + abyte);
      bf16x8 pa1 = *(const bf16x8*)((const char*)&Ps[wid][1][0] + abyte);
#pragma unroll
      for (int dt = 0; dt < 4; dt++) {
        const int d = dt * 16 + lr;
        const int vbyte = d * 128 + (((c * 4 + lg) * 16) ^ ((d & 7) << 4));
        bf16x8 bv = *(const bf16x8*)((const char*)&Vs[cur][0] + vbyte);
        Ot0[dt] = __builtin_amdgcn_mfma_f32_16x16x32_bf16(bv, pa0, Ot0[dt], 0, 0, 0);
        Ot1[dt] = __builtin_amdgcn_mfma_f32_16x16x32_bf16(bv, pa1, Ot1[dt], 0, 0, 0);
      }
    }
    __builtin_amdgcn_s_setprio(0);
  }

  if (ns == 1) {
    const int b = bh >> 4, h = bh & 15;
    {
      const float linv = 1.f / lrow0;
      const size_t base = ((size_t)(b * S_DIM + q0w + lr)) * E_DIM + h * DH_DIM;
#pragma unroll
      for (int dt = 0; dt < 4; dt++) {
        bf16x4 w;
#pragma unroll
        for (int r = 0; r < 4; r++) w[r] = (bf16_t)(Ot0[dt][r] * linv);
        *(bf16x4*)&O[base + dt * 16 + lg * 4] = w;
      }
    }
    {
      const float linv = 1.f / lrow1;
      const size_t base = ((size_t)(b * S_DIM + q0w + 16 + lr)) * E_DIM + h * DH_DIM;
#pragma unroll
      for (int dt = 0; dt < 4; dt++) {
        bf16x4 w;
#pragma unroll
        for (int r = 0; r < 4; r++) w[r] = (bf16_t)(Ot1[dt][r] * linv);
        *(bf16x4*)&O[base + dt * 16 + lg * 4] = w;
      }
    }
  } else {
    const int psl = bh * 48 + (bx - 3);   // pieces with g>=1 start at bx=3
    bf16_t* Ob = Opart + (size_t)psl * 128 * 64;
    const int row0 = wid * 32 + lr, row1 = row0 + 16;
#pragma unroll
    for (int dt = 0; dt < 4; dt++) {
      bf16x4 w0, w1;
#pragma unroll
      for (int r = 0; r < 4; r++) { w0[r] = (bf16_t)Ot0[dt][r]; w1[r] = (bf16_t)Ot1[dt][r]; }
      *(bf16x4*)&Ob[row0 * 64 + dt * 16 + lg * 4] = w0;
      *(bf16x4*)&Ob[row1 * 64 + dt * 16 + lg * 4] = w1;
    }
    if (lg == 0) {
      mpart[psl * 128 + row0] = mrow0;
      lpart[psl * 128 + row0] = lrow0;
      mpart[psl * 128 + row1] = mrow1;
      lpart[psl * 128 + row1] = lrow1;
    }
  }
}

// ---------------- combine partials for q2 >= 3 -------------------------------------
__global__ __launch_bounds__(256) void attn_combine(
    const bf16_t* __restrict__ Opart, const float* __restrict__ mpart,
    const float* __restrict__ lpart, bf16_t* __restrict__ O)
{
  const int q2 = 3 + (blockIdx.x >> 1);
  const int half = blockIdx.x & 1;
  const int bh = blockIdx.y;
  const int g = q2 / 3, ns = g + 1;
  const int sbase = 3 * g * (g + 1) / 2 + (q2 - 3 * g) * (g + 1) - 3;
  const int psl0 = bh * 48 + sbase;
  const int tid = threadIdx.x;
  const int q = tid >> 2, d0 = (tid & 3) * 16;
  const int row = half * 64 + q;

  float M = -1e30f;
  for (int s = 0; s < ns; s++) M = fmaxf(M, mpart[(psl0 + s) * 128 + row]);
  float L = 0.f;
  float acc[16];
#pragma unroll
  for (int j = 0; j < 16; j++) acc[j] = 0.f;
  for (int s = 0; s < ns; s++) {
    const float w = __builtin_exp2f(mpart[(psl0 + s) * 128 + row] - M);
    L += w * lpart[(psl0 + s) * 128 + row];
    const bf16_t* Ob = Opart + ((size_t)(psl0 + s) * 128 + row) * 64 + d0;
    bf16x8 o0 = *(const bf16x8*)Ob;
    bf16x8 o1 = *(const bf16x8*)(Ob + 8);
#pragma unroll
    for (int j = 0; j < 8; j++) { acc[j] += w * (float)o0[j]; acc[8 + j] += w * (float)o1[j]; }
  }
  const float inv = 1.f / L;
  const int b = bh >> 4, h = bh & 15;
  const int srow = q2 * 128 + row;
  bf16_t* out = O + ((size_t)(b * S_DIM + srow)) * E_DIM + h * DH_DIM + d0;
  bf16x8 w0, w1;
#pragma unroll
  for (int j = 0; j < 8; j++) { w0[j] = (bf16_t)(acc[j] * inv); w1[j] = (bf16_t)(acc[8 + j] * inv); }
  *(bf16x8*)out = w0;
  *(bf16x8*)(out + 8) = w1;
}

// ---------------- launcher ---------------------------------------------------------
extern "C" void kernel_launch(void* const* d_in, const int* in_sizes, int n_in,
                              void* d_out, int out_size, void* d_ws, size_t ws_size,
                              hipStream_t stream)
{
  const float* x    = (const float*)d_in[0];
  const float* ln1g = (const float*)d_in[1];
  const float* ln1b = (const float*)d_in[2];
  const float* Wq   = (const float*)d_in[3];
  const float* Wk   = (const float*)d_in[4];
  const float* Wv   = (const float*)d_in[5];
  const float* Wo   = (const float*)d_in[6];
  const float* bo   = (const float*)d_in[7];
  const float* ln2g = (const float*)d_in[8];
  const float* ln2b = (const float*)d_in[9];
  const float* W1   = (const float*)d_in[10];
  const float* b1   = (const float*)d_in[11];
  const float* W2   = (const float*)d_in[12];
  const float* b2   = (const float*)d_in[13];

  char* ws = (char*)d_ws;
  bf16_t* WqkvT = (bf16_t*)(ws + 0);          //  6.29 MB (dead after QKV)
  bf16_t* WoT   = (bf16_t*)(ws + 6291456);    //  2.10 MB (dead after O-proj)
  bf16_t* W1T   = (bf16_t*)(ws + 8388608);    //  8.39 MB (dead after FFN1)
  bf16_t* W2T   = (bf16_t*)(ws + 16777216);   //  8.39 MB
  bf16_t* h1    = (bf16_t*)(ws + 25165824);   //  8.39 MB (dead after QKV)
  bf16_t* qb    = (bf16_t*)(ws + 33554432);   //  8.39 MB (dead after attn)
  bf16_t* kb    = (bf16_t*)(ws + 41943040);   //  8.39 MB
  bf16_t* vb    = (bf16_t*)(ws + 50331648);   //  8.39 MB  [b,h,d,s] transposed
  bf16_t* attnb = (bf16_t*)(ws + 58720256);   //  8.39 MB (dead after O-proj)
  float*  xmid  = (float* )(ws + 67108864);   // 16.78 MB f32
  bf16_t* h2    = (bf16_t*)(ws + 83886080);   //  8.39 MB (dead after FFN1)
  bf16_t* ff1   = (bf16_t*)(ws + 25165824);   // 33.55 MB over h1/qb/kb/vb
  bf16_t* Opart = (bf16_t*)(ws + 67108864);   // 25.17 MB [32*48][128][64] (over xmid/h2)
  float*  mpart = (float* )(ws + 25165824);   //  0.79 MB (over h1, consumed pre-O-proj)
  float*  lpart = (float* )(ws + 25952256);   //  0.79 MB
  bf16_t* po0   = (bf16_t*)(ws + 25165824);   //  8.39 MB O-proj bf16 partial (over h1)
  bf16_t* po1   = (bf16_t*)(ws + 33554432);   //  8.39 MB (over qb, dead post-attn)
  bf16_t* pf0   = (bf16_t*)(ws + 0);          // FFN2 partials over dead regions
  bf16_t* pf1   = (bf16_t*)(ws + 8388608);
  bf16_t* pf2   = (bf16_t*)(ws + 58720256);
  bf16_t* pf3   = (bf16_t*)(ws + 83886080);

  pack_weights<<<3072, 256, 0, stream>>>(Wq, Wk, Wv, WqkvT, Wo, WoT, W1, W1T, W2, W2T);

  ln_kernel<<<4096, 256, 0, stream>>>(x, ln1g, ln1b, h1);
  // QKV on 8-phase gemm256: grid 16m x 12n; regions 8x3 (2 x 4 region grid)
  gemm256_kernel<EPI_QKV><<<dim3(16, 12, 1), 512, 0, stream>>>(
      h1, WqkvT, 4096, 3072, 1024, 1024, 8, 3, nullptr,
      nullptr, nullptr, qb, kb, vb);
  attn_kernel<<<dim3(51, 32), 256, 0, stream>>>(qb, kb, vb, attnb, Opart, mpart, lpart);
  attn_combine<<<dim3(26, 32), 256, 0, stream>>>(Opart, mpart, lpart, attnb);
  // O-proj: per z grid 32m x 8n; regions 8x4 (4 x 2)
  gemm128_kernel<EPI_PART_B16><<<dim3(32, 8, 2), 256, 0, stream>>>(
      attnb, WoT, 4096, 1024, 1024, 512, 8, 4, nullptr,
      nullptr, po0, po1, nullptr, nullptr);
  reduce2_ln<<<4096, 256, 0, stream>>>(po0, po1, bo, x, ln2g, ln2b, xmid, h2);
  // FFN1: grid 16m x 16n; regions 8x4 (2 x 4)
  gemm256_kernel<EPI_BIAS_RELU><<<dim3(16, 16, 1), 512, 0, stream>>>(
      h2, W1T, 4096, 4096, 1024, 1024, 8, 4, b1,
      nullptr, ff1, nullptr, nullptr, nullptr);
  // FFN2: per z grid 16m x 4n; regions 4x2 (4 x 2)
  gemm256_kernel<EPI_PART_B16><<<dim3(16, 4, 4), 512, 0, stream>>>(
      ff1, W2T, 4096, 1024, 4096, 1024, 4, 2, nullptr,
      nullptr, pf0, pf1, pf2, pf3);
  reduce4<<<4096, 256, 0, stream>>>(pf0, pf1, pf2, pf3, b2, xmid, (float*)d_out);

  (void)in_sizes; (void)n_in; (void)out_size; (void)ws_size;
}

// Round 20
// 238.915 us; speedup vs baseline: 1.0334x; 1.0334x over previous
//
#include <hip/hip_runtime.h>

// TransformerBlock on MI355X: LN1 -> QKV -> causal MHA -> O-proj+res -> LN2 -> FFN+res
// R20 = exact revert to R17 (measured optimum 239.2us): QKV/O-proj on 2-phase BK=64
// gemm128 (2 blocks/CU, scatter epilogue amortized); FFN1/FFN2 on 8-phase
// counted-vmcnt gemm256 (T3+T4). R18 (8-phase gemm128) and R19 (QKV on gemm256)
// both regressed: 8-phase needs >=16-MFMA phases AND full CU fill AND streaming
// epilogue. Attention: 128 q-rows/block, uniform <=6-chunk KV pieces, swapped
// QK^T/PV, defer-max -- structurally pinned at ~57us.

typedef __bf16 bf16_t;
typedef __attribute__((ext_vector_type(8))) __bf16 bf16x8;
typedef __attribute__((ext_vector_type(4))) __bf16 bf16x4;
typedef __attribute__((ext_vector_type(4))) float f32x4;

#define B_DIM 2
#define S_DIM 2048
#define E_DIM 1024
#define H_DIM 16
#define DH_DIM 64

#define GLD16(gp, lp) __builtin_amdgcn_global_load_lds( \
    (const __attribute__((address_space(1))) void*)(gp), \
    (__attribute__((address_space(3))) void*)(lp), 16, 0, 0)

// fold E^-0.5 (=1/32) and log2(e) into Q so softmax can use exp2 directly
#define Q_SCALE 0.0450842120f

// ---------------- LayerNorm: fp32 in -> bf16 out (one block per row) -------------
__global__ __launch_bounds__(256) void ln_kernel(
    const float* __restrict__ x, const float* __restrict__ g,
    const float* __restrict__ bv, bf16_t* __restrict__ out)
{
  const int row = blockIdx.x;
  const int t = threadIdx.x;
  const float* xr = x + (size_t)row * E_DIM;
  float4 v = *(const float4*)&xr[t * 4];
  float s  = v.x + v.y + v.z + v.w;
  float s2 = v.x*v.x + v.y*v.y + v.z*v.z + v.w*v.w;
#pragma unroll
  for (int m = 1; m < 64; m <<= 1) {
    s  += __shfl_xor(s,  m, 64);
    s2 += __shfl_xor(s2, m, 64);
  }
  __shared__ float red[8];
  const int wid = t >> 6, lane = t & 63;
  if (lane == 0) { red[wid] = s; red[4 + wid] = s2; }
  __syncthreads();
  s  = red[0] + red[1] + red[2] + red[3];
  s2 = red[4] + red[5] + red[6] + red[7];
  const float mu  = s * (1.f / E_DIM);
  const float var = s2 * (1.f / E_DIM) - mu * mu;
  const float rs  = rsqrtf(var + 1e-5f);
  float4 gg = *(const float4*)&g[t * 4];
  float4 bb = *(const float4*)&bv[t * 4];
  bf16x4 o;
  o[0] = (bf16_t)((v.x - mu) * rs * gg.x + bb.x);
  o[1] = (bf16_t)((v.y - mu) * rs * gg.y + bb.y);
  o[2] = (bf16_t)((v.z - mu) * rs * gg.z + bb.z);
  o[3] = (bf16_t)((v.w - mu) * rs * gg.w + bb.w);
  *(bf16x4*)&out[(size_t)row * E_DIM + t * 4] = o;
}

// ---- O-proj split-K combine (2 bf16 partials) + bias + residual -> xmid, LN2 -> h2
__global__ __launch_bounds__(256) void reduce2_ln(
    const bf16_t* __restrict__ p0, const bf16_t* __restrict__ p1,
    const float* __restrict__ bo, const float* __restrict__ x,
    const float* __restrict__ g, const float* __restrict__ bv,
    float* __restrict__ xmid, bf16_t* __restrict__ h2)
{
  const int row = blockIdx.x;
  const int t = threadIdx.x;
  const size_t off = (size_t)row * E_DIM + t * 4;
  bf16x4 a = *(const bf16x4*)&p0[off];
  bf16x4 b4 = *(const bf16x4*)&p1[off];
  float4 xr = *(const float4*)&x[off];
  float4 bo4 = *(const float4*)&bo[t * 4];
  float4 v;
  v.x = (float)a[0] + (float)b4[0] + xr.x + bo4.x;
  v.y = (float)a[1] + (float)b4[1] + xr.y + bo4.y;
  v.z = (float)a[2] + (float)b4[2] + xr.z + bo4.z;
  v.w = (float)a[3] + (float)b4[3] + xr.w + bo4.w;
  *(float4*)&xmid[off] = v;
  float s  = v.x + v.y + v.z + v.w;
  float s2 = v.x*v.x + v.y*v.y + v.z*v.z + v.w*v.w;
#pragma unroll
  for (int m = 1; m < 64; m <<= 1) {
    s  += __shfl_xor(s,  m, 64);
    s2 += __shfl_xor(s2, m, 64);
  }
  __shared__ float red[8];
  const int wid = t >> 6, lane = t & 63;
  if (lane == 0) { red[wid] = s; red[4 + wid] = s2; }
  __syncthreads();
  s  = red[0] + red[1] + red[2] + red[3];
  s2 = red[4] + red[5] + red[6] + red[7];
  const float mu  = s * (1.f / E_DIM);
  const float var = s2 * (1.f / E_DIM) - mu * mu;
  const float rs  = rsqrtf(var + 1e-5f);
  float4 gg = *(const float4*)&g[t * 4];
  float4 bb = *(const float4*)&bv[t * 4];
  bf16x4 o;
  o[0] = (bf16_t)((v.x - mu) * rs * gg.x + bb.x);
  o[1] = (bf16_t)((v.y - mu) * rs * gg.y + bb.y);
  o[2] = (bf16_t)((v.z - mu) * rs * gg.z + bb.z);
  o[3] = (bf16_t)((v.w - mu) * rs * gg.w + bb.w);
  *(bf16x4*)&h2[off] = o;
}

// ---- FFN2 split-K combine (4 bf16 partials) + bias + residual -> d_out (f32) -----
__global__ __launch_bounds__(256) void reduce4(
    const bf16_t* __restrict__ p0, const bf16_t* __restrict__ p1,
    const bf16_t* __restrict__ p2, const bf16_t* __restrict__ p3,
    const float* __restrict__ b2, const float* __restrict__ xm,
    float* __restrict__ out)
{
  const int row = blockIdx.x;
  const int t = threadIdx.x;
  const size_t off = (size_t)row * E_DIM + t * 4;
  bf16x4 a0 = *(const bf16x4*)&p0[off];
  bf16x4 a1 = *(const bf16x4*)&p1[off];
  bf16x4 a2 = *(const bf16x4*)&p2[off];
  bf16x4 a3 = *(const bf16x4*)&p3[off];
  float4 xr = *(const float4*)&xm[off];
  float4 bb = *(const float4*)&b2[t * 4];
  float4 o;
  o.x = (float)a0[0] + (float)a1[0] + (float)a2[0] + (float)a3[0] + xr.x + bb.x;
  o.y = (float)a0[1] + (float)a1[1] + (float)a2[1] + (float)a3[1] + xr.y + bb.y;
  o.z = (float)a0[2] + (float)a1[2] + (float)a2[2] + (float)a3[2] + xr.z + bb.z;
  o.w = (float)a0[3] + (float)a1[3] + (float)a2[3] + (float)a3[3] + xr.w + bb.w;
  *(float4*)&out[off] = o;
}

// -------- fused weight pack: all four transposes in ONE launch ---------------------
__global__ __launch_bounds__(256) void pack_weights(
    const float* __restrict__ Wq, const float* __restrict__ Wk,
    const float* __restrict__ Wv, bf16_t* __restrict__ WqkvT,
    const float* __restrict__ Wo, bf16_t* __restrict__ WoT,
    const float* __restrict__ W1, bf16_t* __restrict__ W1T,
    const float* __restrict__ W2, bf16_t* __restrict__ W2T)
{
  __shared__ float tile[64][65];
  const int bid = blockIdx.x;
  const int t = threadIdx.x;
  const int rr = t >> 2;

  if (bid < 768) {
    const int byq = bid >> 4, bxq = bid & 15;
    const int m = byq >> 4, h = byq & 15;
    const float* src = (m == 0 ? Wq : (m == 1 ? Wk : Wv)) + (size_t)h * E_DIM * DH_DIM;
    const int e0 = bxq * 64;
#pragma unroll
    for (int u = 0; u < 4; u++) {
      const int cc = (t & 3) * 4 + u * 16;
      float4 f = *(const float4*)&src[(size_t)(e0 + rr) * DH_DIM + cc];
      tile[rr][cc + 0] = f.x; tile[rr][cc + 1] = f.y;
      tile[rr][cc + 2] = f.z; tile[rr][cc + 3] = f.w;
    }
    __syncthreads();
    const int oc = t >> 2;  // d index 0..63
    const size_t drow = (size_t)(m * 1024 + h * 64 + oc) * E_DIM;
#pragma unroll
    for (int u = 0; u < 4; u++) {
      const int orr = (t & 3) * 4 + u * 16;
      bf16x4 w;
      w[0] = (bf16_t)tile[orr + 0][oc];
      w[1] = (bf16_t)tile[orr + 1][oc];
      w[2] = (bf16_t)tile[orr + 2][oc];
      w[3] = (bf16_t)tile[orr + 3][oc];
      *(bf16x4*)&WqkvT[drow + e0 + orr] = w;
    }
    return;
  }

  const float* src; bf16_t* dst; int R, C, bx, by;
  if (bid < 1024)      { const int r = bid - 768;  src = Wo; dst = WoT; R = 1024; C = 1024; bx = r & 15; by = r >> 4; }
  else if (bid < 2048) { const int r = bid - 1024; src = W1; dst = W1T; R = 1024; C = 4096; bx = r & 63; by = r >> 6; }
  else                 { const int r = bid - 2048; src = W2; dst = W2T; R = 4096; C = 1024; bx = r & 15; by = r >> 4; }
  const int c0 = bx * 64, r0 = by * 64;
#pragma unroll
  for (int u = 0; u < 4; u++) {
    const int cc = (t & 3) * 4 + u * 16;
    float4 f = *(const float4*)&src[(size_t)(r0 + rr) * C + c0 + cc];
    tile[rr][cc + 0] = f.x; tile[rr][cc + 1] = f.y;
    tile[rr][cc + 2] = f.z; tile[rr][cc + 3] = f.w;
  }
  __syncthreads();
  const int oc = t >> 2;
#pragma unroll
  for (int u = 0; u < 4; u++) {
    const int orr = (t & 3) * 4 + u * 16;
    bf16x4 w;
    w[0] = (bf16_t)tile[orr + 0][oc];
    w[1] = (bf16_t)tile[orr + 1][oc];
    w[2] = (bf16_t)tile[orr + 2][oc];
    w[3] = (bf16_t)tile[orr + 3][oc];
    *(bf16x4*)&dst[(size_t)(c0 + oc) * R + r0 + orr] = w;
  }
}

constexpr int EPI_QKV = 0, EPI_BIAS_RELU = 2, EPI_PART_F32 = 3, EPI_PART_B16 = 4;

// XCD-region swizzle (all GEMMs): lin = by*gx+bx; xcd = lin&7; k = lin>>3.
// 8 regions of RM x RN blocks; within region m-minor (B-panel reuse, A panels in L2).

// ------------- 128x128-tile MFMA GEMM, BK=64, 2-phase pipeline ---------------------
// LDS rows 128B: global (row r, 8-elem group u of 8) at byte r*128 + (u^(r&7))*16.
template <int EPI>
__global__ __launch_bounds__(256) void gemm128_kernel(
    const bf16_t* __restrict__ A, const bf16_t* __restrict__ Bt,
    int M, int N, int Kst, int Klen, int RM, int RN,
    const float* __restrict__ bias,
    float* __restrict__ outF, bf16_t* __restrict__ outB,
    bf16_t* __restrict__ qo, bf16_t* __restrict__ ko, bf16_t* __restrict__ vo)
{
  __shared__ bf16_t As[2][128 * 64];   // 32KB
  __shared__ bf16_t Bs[2][128 * 64];   // 32KB
  const int gx = gridDim.x;
  const int lin = blockIdx.y * gx + blockIdx.x;
  const int xcd = lin & 7, kb = lin >> 3;
  const int nregx = gx / RM;
  const int rx = xcd % nregx, ry = xcd / nregx;
  const int m0 = (rx * RM + kb % RM) * 128;
  const int n0 = (ry * RN + kb / RM) * 128;
  const int sp = blockIdx.z;
  A  += (size_t)sp * Klen;
  Bt += (size_t)sp * Klen;

  const int tid = threadIdx.x, lane = tid & 63, wid = tid >> 6;
  const int wr = wid >> 1, wc = wid & 1;
  const int lr = lane & 15, lg = lane >> 4;
  const int l7 = lr & 7;
  const int sl[2] = { (lg ^ l7) * 16, ((4 | lg) ^ l7) * 16 };  // kk = 0, 1
  const int rbA = (wr * 64 + lr) * 128;   // + i*2048
  const int rbB = (wc * 64 + lr) * 128;   // + j*2048

  auto stage = [&](int kt, int buf) {
#pragma unroll
    for (int q = 0; q < 4; q++) {
      const int L = q * 256 + tid;
      const int row = L >> 3;
      const int u = (L & 7) ^ (row & 7);
      char* la = (char*)&As[buf][0] + (size_t)(q * 256 + wid * 64) * 16;
      char* lb = (char*)&Bs[buf][0] + (size_t)(q * 256 + wid * 64) * 16;
      GLD16(A  + (size_t)(m0 + row) * Kst + kt * 64 + u * 8, la);
      GLD16(Bt + (size_t)(n0 + row) * Kst + kt * 64 + u * 8, lb);
    }
  };

  const f32x4 z4 = {0.f, 0.f, 0.f, 0.f};
  f32x4 acc[4][4];
#pragma unroll
  for (int i = 0; i < 4; i++)
#pragma unroll
    for (int j = 0; j < 4; j++) acc[i][j] = z4;

  const int NT = Klen / 64;
  stage(0, 0);
  for (int T = 0; T < NT; ++T) {
    const int b = T & 1;
    asm volatile("s_waitcnt vmcnt(0)" ::: "memory");  // own stage(T) landed
    __builtin_amdgcn_s_barrier();                     // everyone's stage(T) visible
    if (T + 1 < NT) stage(T + 1, b ^ 1);              // flies under compute T
    __builtin_amdgcn_sched_barrier(0);

    bf16x8 bfr[2][4];
#pragma unroll
    for (int kk = 0; kk < 2; kk++)
#pragma unroll
      for (int j = 0; j < 4; j++)
        bfr[kk][j] = *(const bf16x8*)((const char*)&Bs[b][0] + rbB + j * 2048 + sl[kk]);
    __builtin_amdgcn_s_setprio(1);
#pragma unroll
    for (int i = 0; i < 4; i++) {
#pragma unroll
      for (int kk = 0; kk < 2; kk++) {
        bf16x8 af = *(const bf16x8*)((const char*)&As[b][0] + rbA + i * 2048 + sl[kk]);
#pragma unroll
        for (int j = 0; j < 4; j++)
          acc[i][j] = __builtin_amdgcn_mfma_f32_16x16x32_bf16(af, bfr[kk][j], acc[i][j], 0, 0, 0);
      }
    }
    __builtin_amdgcn_s_setprio(0);
  }

#pragma unroll
  for (int i = 0; i < 4; i++) {
#pragma unroll
    for (int j = 0; j < 4; j++) {
#pragma unroll
      for (int r = 0; r < 4; r++) {
        const int m = m0 + wr * 64 + i * 16 + lg * 4 + r;
        const int n = n0 + wc * 64 + j * 16 + lr;
        const float val = acc[i][j][r];
        if constexpr (EPI == EPI_QKV) {
          const int tsel = n >> 10, h = (n >> 6) & 15, d = n & 63;
          const int b_ = m >> 11, s_ = m & 2047;
          if (tsel == 0)
            qo[((size_t)((b_ * H_DIM + h) * S_DIM + s_)) * DH_DIM + d] = (bf16_t)(val * Q_SCALE);
          else if (tsel == 1)
            ko[((size_t)((b_ * H_DIM + h) * S_DIM + s_)) * DH_DIM + d] = (bf16_t)val;
          else  // V stored transposed: [b,h,d,s]
            vo[((size_t)((b_ * H_DIM + h) * DH_DIM + d)) * S_DIM + s_] = (bf16_t)val;
        } else if constexpr (EPI == EPI_BIAS_RELU) {
          const float u = val + bias[n];
          outB[(size_t)m * N + n] = (bf16_t)(u > 0.f ? u : 0.f);
        } else if constexpr (EPI == EPI_PART_F32) {
          outF[(size_t)sp * M * N + (size_t)m * N + n] = val;
        } else {
          bf16_t* o = sp == 0 ? outB : sp == 1 ? qo : sp == 2 ? ko : vo;
          o[(size_t)m * N + n] = (bf16_t)val;
        }
      }
    }
  }
}

// ------------- 256x256-tile MFMA GEMM, BK=64, 8-phase counted-vmcnt ----------------
// LDS [2 buf][2 k-half] per matrix; each half = paired-row [128 pairs][128B]:
// global (row r, 8-group u of 4) at byte (r>>1)*128 + (((r&1)*4+u)^((r>>1)&7))*16.
// Phases per tile: q = (kh<<1|mh): 4 A-frag ds_reads (+4 B-frags when entering kh),
// issue stage unit q of tile TT+1, 16 MFMA, barrier. vmcnt(4) at ends of phases 1
// and 3 (FIFO proves the units needed next while 2 newest stay in flight).
template <int EPI>
__global__ __launch_bounds__(512) void gemm256_kernel(
    const bf16_t* __restrict__ A, const bf16_t* __restrict__ Bt,
    int M, int N, int Kst, int Klen, int RM, int RN,
    const float* __restrict__ bias,
    float* __restrict__ outF, bf16_t* __restrict__ outB,
    bf16_t* __restrict__ qo, bf16_t* __restrict__ ko, bf16_t* __restrict__ vo)
{
  __shared__ bf16_t As[2][2][128 * 64];   // [buf][kh] 16KB each -> 64KB
  __shared__ bf16_t Bs[2][2][128 * 64];   // 64KB
  const int gx = gridDim.x;
  const int lin = blockIdx.y * gx + blockIdx.x;
  const int xcd = lin & 7, kb = lin >> 3;
  const int nregx = gx / RM;
  const int rx = xcd % nregx, ry = xcd / nregx;
  const int m0 = (rx * RM + kb % RM) * 256;
  const int n0 = (ry * RN + kb / RM) * 256;
  const int sp = blockIdx.z;
  A  += (size_t)sp * Klen;
  Bt += (size_t)sp * Klen;

  const int tid = threadIdx.x, lane = tid & 63, wid = tid >> 6;
  const int wm = wid >> 2, wn = wid & 3;
  const int lr = lane & 15, lg = lane >> 4;
  const int sl16 = (((lr & 1) * 4 + lg) ^ ((lr >> 1) & 7)) * 16;  // lane-constant
  const int rbA = (wm * 64 + (lr >> 1)) * 128 + sl16;   // + i*1024 within As[buf][kh]
  const int rbB = (wn * 32 + (lr >> 1)) * 128 + sl16;   // + j*1024 within Bs[buf][kh]

  // stage one unit: matrix (matB), k-half kh of tile kt -> 2 GLD16/thread (16KB)
  auto stageU = [&](int kt, int kh, int matB) {
    const int buf = kt & 1;
#pragma unroll
    for (int p = 0; p < 2; p++) {
      const int L = p * 512 + tid;
      const int row2 = L >> 3;
      const int s = (L & 7) ^ (row2 & 7);
      const int r = row2 * 2 + (s >> 2);
      const int u = s & 3;
      char* lds = (char*)(matB ? &Bs[buf][kh][0] : &As[buf][kh][0])
                + (size_t)(p * 512 + wid * 64) * 16;
      const bf16_t* gp = (matB ? Bt + (size_t)(n0 + r) * Kst
                               : A  + (size_t)(m0 + r) * Kst)
                       + kt * 64 + kh * 32 + u * 8;
      GLD16(gp, lds);
    }
  };

  const f32x4 z4 = {0.f, 0.f, 0.f, 0.f};
  f32x4 acc[8][4];
#pragma unroll
  for (int i = 0; i < 8; i++)
#pragma unroll
    for (int j = 0; j < 4; j++) acc[i][j] = z4;

  const int NT = Klen / 64;
  // prologue: all 4 units of tile 0; prove units 0,1 (kh0) before phase 0 reads
  stageU(0, 0, 0); stageU(0, 0, 1); stageU(0, 1, 0); stageU(0, 1, 1);
  asm volatile("s_waitcnt vmcnt(4)" ::: "memory");
  __builtin_amdgcn_s_barrier();
  __builtin_amdgcn_sched_barrier(0);

  for (int TT = 0; TT < NT; ++TT) {
    const int buf = TT & 1;
    bf16x8 bfr[4];
#pragma unroll
    for (int q = 0; q < 4; q++) {
      const int kh = q >> 1, mh = q & 1;
      if ((q & 1) == 0) {
#pragma unroll
        for (int j = 0; j < 4; j++)
          bfr[j] = *(const bf16x8*)((const char*)&Bs[buf][kh][0] + rbB + j * 1024);
      }
      bf16x8 af[4];
#pragma unroll
      for (int ii = 0; ii < 4; ii++)
        af[ii] = *(const bf16x8*)((const char*)&As[buf][kh][0] + rbA + (mh * 4 + ii) * 1024);
      if (TT + 1 < NT) stageU(TT + 1, q >> 1, q & 1);
      __builtin_amdgcn_s_setprio(1);
#pragma unroll
      for (int ii = 0; ii < 4; ii++)
#pragma unroll
        for (int j = 0; j < 4; j++)
          acc[mh * 4 + ii][j] =
              __builtin_amdgcn_mfma_f32_16x16x32_bf16(af[ii], bfr[j], acc[mh * 4 + ii][j], 0, 0, 0);
      __builtin_amdgcn_s_setprio(0);
      if (q & 1) {
        __builtin_amdgcn_sched_barrier(0);
        if (TT + 1 < NT) asm volatile("s_waitcnt vmcnt(4)" ::: "memory");
        else if (q == 1) asm volatile("s_waitcnt vmcnt(0)" ::: "memory");
      }
      __builtin_amdgcn_s_barrier();
      __builtin_amdgcn_sched_barrier(0);
    }
  }

#pragma unroll
  for (int i = 0; i < 8; i++) {
#pragma unroll
    for (int j = 0; j < 4; j++) {
#pragma unroll
      for (int r = 0; r < 4; r++) {
        const int m = m0 + wm * 128 + i * 16 + lg * 4 + r;
        const int n = n0 + wn * 64 + j * 16 + lr;
        const float val = acc[i][j][r];
        if constexpr (EPI == EPI_BIAS_RELU) {
          const float u = val + bias[n];
          outB[(size_t)m * N + n] = (bf16_t)(u > 0.f ? u : 0.f);
        } else if constexpr (EPI == EPI_PART_F32) {
          outF[(size_t)sp * M * N + (size_t)m * N + n] = val;
        } else if constexpr (EPI == EPI_PART_B16) {
          bf16_t* o = sp == 0 ? outB : sp == 1 ? qo : sp == 2 ? ko : vo;
          o[(size_t)m * N + n] = (bf16_t)val;
        }
      }
    }
  }
}

// ---------------- causal flash attention: 128 q-rows/block, uniform KV pieces ------
__global__ __launch_bounds__(256) void attn_kernel(
    const bf16_t* __restrict__ Q, const bf16_t* __restrict__ K,
    const bf16_t* __restrict__ Vt, bf16_t* __restrict__ O,
    bf16_t* __restrict__ Opart, float* __restrict__ mpart, float* __restrict__ lpart)
{
  __shared__ bf16_t Ks[2][64 * 64];      // [t][d], 16B slot ^= (t&7)
  __shared__ bf16_t Vs[2][64 * 64];      // [d][t], 16B slot ^= (d&7)
  __shared__ bf16_t Ps[4][2][16 * 64];   // per-wave, per-sub [q][t], slot ^= (q&7)

  const int nwg = 51 * gridDim.y;
  int id = blockIdx.y * 51 + blockIdx.x;
  id = (id & 7) * (nwg >> 3) + (id >> 3);
  const int bx = id % 51, bh = id / 51;

  int g = 0;
  while (3 * (g + 1) * (g + 2) / 2 <= bx) g++;      // <=5 iterations
  const int rr_ = bx - 3 * g * (g + 1) / 2;
  const int q2 = 3 * g + rr_ / (g + 1);
  const int sp = rr_ % (g + 1);
  const int ns = g + 1;
  const int n2 = 2 * q2 + 2;
  const int lo = 6 * sp;
  const int hi = (6 * sp + 6 < n2) ? 6 * sp + 6 : n2;

  const int tid = threadIdx.x;
  const int wid = tid >> 6, lane = tid & 63;
  const int lr = lane & 15, lg = lane >> 4;
  const int q0w = q2 * 128 + wid * 32;   // wave's 32 q rows; subs at +0, +16

  const bf16_t* Qp = Q  + (size_t)bh * S_DIM * DH_DIM;
  const bf16_t* Kp = K  + (size_t)bh * S_DIM * DH_DIM;
  const bf16_t* Vp = Vt + (size_t)bh * DH_DIM * S_DIM;  // [d][s]

  bf16x8 bq0[2], bq1[2];
#pragma unroll
  for (int c = 0; c < 2; c++) {
    bq0[c] = *(const bf16x8*)&Qp[(size_t)(q0w + lr) * DH_DIM + c * 32 + lg * 8];
    bq1[c] = *(const bf16x8*)&Qp[(size_t)(q0w + 16 + lr) * DH_DIM + c * 32 + lg * 8];
  }

  const f32x4 z4 = {0.f, 0.f, 0.f, 0.f};
  f32x4 Ot0[4], Ot1[4];   // O^T: Ot[dt][r] = O[q][d = dt*16 + lg*4 + r]
#pragma unroll
  for (int dt = 0; dt < 4; dt++) { Ot0[dt] = z4; Ot1[dt] = z4; }
  float mrow0 = -1e30f, lrow0 = 0.f;   // per-lane state, q = q0w + lr
  float mrow1 = -1e30f, lrow1 = 0.f;   // q = q0w + 16 + lr

  const int ktr = wid * 8 + (lane >> 3);
  const int ksc = lane & 7;

  auto stageKV = [&](int t0, int buf) {
#pragma unroll
    for (int p = 0; p < 2; p++) {
      const int tr = p * 32 + ktr;
      GLD16(Kp + (size_t)(t0 + tr) * DH_DIM + (ksc ^ (tr & 7)) * 8,
            &Ks[buf][(p * 32 + wid * 8) * 64]);
      GLD16(Vp + (size_t)tr * S_DIM + t0 + (ksc ^ (tr & 7)) * 8,
            &Vs[buf][(p * 32 + wid * 8) * 64]);
    }
  };

  stageKV(lo * 64, 0);

  for (int tc = lo; tc < hi; ++tc) {
    const int cur = (tc - lo) & 1;
    __syncthreads();                       // drains stageKV(tc); prev buf free
    if (tc + 1 < hi) stageKV((tc + 1) * 64, cur ^ 1);

    const int t0 = tc * 64;
    f32x4 s0[4], s1[4];
    __builtin_amdgcn_s_setprio(1);
#pragma unroll
    for (int j = 0; j < 4; j++) {
      f32x4 a = z4, b = z4;
      const int t = j * 16 + lr;
#pragma unroll
      for (int c = 0; c < 2; c++) {
        const int kbyte = t * 128 + (((c * 4 + lg) * 16) ^ ((t & 7) << 4));
        bf16x8 ak = *(const bf16x8*)((const char*)&Ks[cur][0] + kbyte);
        a = __builtin_amdgcn_mfma_f32_16x16x32_bf16(ak, bq0[c], a, 0, 0, 0);
        b = __builtin_amdgcn_mfma_f32_16x16x32_bf16(ak, bq1[c], b, 0, 0, 0);
      }
      s0[j] = a; s1[j] = b;
    }
    __builtin_amdgcn_s_setprio(0);
    if (tc >= 2 * q2) {   // chunks overlapping the block's causal diagonal
#pragma unroll
      for (int j = 0; j < 4; j++)
#pragma unroll
        for (int r = 0; r < 4; r++) {
          const int tg = t0 + j * 16 + lg * 4 + r;
          if (tg > q0w + lr)      s0[j][r] = -1e30f;
          if (tg > q0w + 16 + lr) s1[j][r] = -1e30f;
        }
    }
    // ---- softmax sub0 ----
    {
      float mj[4];
#pragma unroll
      for (int j = 0; j < 4; j++)
        mj[j] = fmaxf(fmaxf(s0[j][0], s0[j][1]), fmaxf(s0[j][2], s0[j][3]));
      float tmax = fmaxf(fmaxf(mj[0], mj[1]), fmaxf(mj[2], mj[3]));
      tmax = fmaxf(tmax, __shfl_xor(tmax, 16, 64));
      tmax = fmaxf(tmax, __shfl_xor(tmax, 32, 64));
      if (!__all(tmax <= mrow0 + 8.f)) {
        const float mnew = fmaxf(mrow0, tmax);
        const float fsc = __builtin_exp2f(mrow0 - mnew);
        mrow0 = mnew; lrow0 *= fsc;
#pragma unroll
        for (int dt = 0; dt < 4; dt++)
#pragma unroll
          for (int r = 0; r < 4; r++) Ot0[dt][r] *= fsc;
      }
      float sj[4];
#pragma unroll
      for (int j = 0; j < 4; j++) {
#pragma unroll
        for (int r = 0; r < 4; r++) s0[j][r] = __builtin_exp2f(s0[j][r] - mrow0);
        sj[j] = (s0[j][0] + s0[j][1]) + (s0[j][2] + s0[j][3]);
      }
      float tsum = (sj[0] + sj[1]) + (sj[2] + sj[3]);
      tsum += __shfl_xor(tsum, 16, 64);
      tsum += __shfl_xor(tsum, 32, 64);
      lrow0 += tsum;
#pragma unroll
      for (int j = 0; j < 4; j++) {
        bf16x4 w;
#pragma unroll
        for (int r = 0; r < 4; r++) w[r] = (bf16_t)s0[j][r];
        const int pbyte = lr * 128 + ((j * 32 + lg * 8) ^ ((lr & 7) << 4));
        *(bf16x4*)((char*)&Ps[wid][0][0] + pbyte) = w;
      }
    }
    // ---- softmax sub1 ----
    {
      float mj[4];
#pragma unroll
      for (int j = 0; j < 4; j++)
        mj[j] = fmaxf(fmaxf(s1[j][0], s1[j][1]), fmaxf(s1[j][2], s1[j][3]));
      float tmax = fmaxf(fmaxf(mj[0], mj[1]), fmaxf(mj[2], mj[3]));
      tmax = fmaxf(tmax, __shfl_xor(tmax, 16, 64));
      tmax = fmaxf(tmax, __shfl_xor(tmax, 32, 64));
      if (!__all(tmax <= mrow1 + 8.f)) {
        const float mnew = fmaxf(mrow1, tmax);
        const float fsc = __builtin_exp2f(mrow1 - mnew);
        mrow1 = mnew; lrow1 *= fsc;
#pragma unroll
        for (int dt = 0; dt < 4; dt++)
#pragma unroll
          for (int r = 0; r < 4; r++) Ot1[dt][r] *= fsc;
      }
      float sj[4];
#pragma unroll
      for (int j = 0; j < 4; j++) {
#pragma unroll
        for (int r = 0; r < 4; r++) s1[j][r] = __builtin_exp2f(s1[j][r] - mrow1);
        sj[j] = (s1[j][0] + s1[j][1]) + (s1[j][2] + s1[j][3]);
      }
      float tsum = (sj[0] + sj[1]) + (sj[2] + sj[3]);
      tsum += __shfl_xor(tsum, 16, 64);
      tsum += __shfl_xor(tsum, 32, 64);
      lrow1 += tsum;
#pragma unroll
      for (int j = 0; j < 4; j++) {
        bf16x4 w;
#pragma unroll
        for (int r = 0; r < 4; r++) w[r] = (bf16_t)s1[j][r];
        const int pbyte = lr * 128 + ((j * 32 + lg * 8) ^ ((lr & 7) << 4));
        *(bf16x4*)((char*)&Ps[wid][1][0] + pbyte) = w;
      }
    }

    // PV swapped, V-fragments shared across subs: Ot = mfma(bv, pa)
    __builtin_amdgcn_s_setprio(1);
#pragma unroll
    for (int c = 0; c < 2; c++) {
      const int abyte = lr * 128 + ((c * 64 + lg * 16) ^ ((lr & 7) << 4));
      bf16x8 pa0 = *(const bf16x8*)((const char*)&Ps[wid][0][0] + abyte);
      bf16x8 pa1 = *(const bf16x8*)((const char*)&Ps[wid][1][0] + abyte);
#pragma unroll
      for (int dt = 0; dt < 4; dt++) {
        const int d = dt * 16 + lr;
        const int vbyte = d * 128 + (((c * 4 + lg) * 16) ^ ((d & 7) << 4));
        bf16x8 bv = *(const bf16x8*)((const char*)&Vs[cur][0] + vbyte);
        Ot0[dt] = __builtin_amdgcn_mfma_f32_16x16x32_bf16(bv, pa0, Ot0[dt], 0, 0, 0);
        Ot1[dt] = __builtin_amdgcn_mfma_f32_16x16x32_bf16(bv, pa1, Ot1[dt], 0, 0, 0);
      }
    }
    __builtin_amdgcn_s_setprio(0);
  }

  if (ns == 1) {
    const int b = bh >> 4, h = bh & 15;
    {
      const float linv = 1.f / lrow0;
      const size_t base = ((size_t)(b * S_DIM + q0w + lr)) * E_DIM + h * DH_DIM;
#pragma unroll
      for (int dt = 0; dt < 4; dt++) {
        bf16x4 w;
#pragma unroll
        for (int r = 0; r < 4; r++) w[r] = (bf16_t)(Ot0[dt][r] * linv);
        *(bf16x4*)&O[base + dt * 16 + lg * 4] = w;
      }
    }
    {
      const float linv = 1.f / lrow1;
      const size_t base = ((size_t)(b * S_DIM + q0w + 16 + lr)) * E_DIM + h * DH_DIM;
#pragma unroll
      for (int dt = 0; dt < 4; dt++) {
        bf16x4 w;
#pragma unroll
        for (int r = 0; r < 4; r++) w[r] = (bf16_t)(Ot1[dt][r] * linv);
        *(bf16x4*)&O[base + dt * 16 + lg * 4] = w;
      }
    }
  } else {
    const int psl = bh * 48 + (bx - 3);   // pieces with g>=1 start at bx=3
    bf16_t* Ob = Opart + (size_t)psl * 128 * 64;
    const int row0 = wid * 32 + lr, row1 = row0 + 16;
#pragma unroll
    for (int dt = 0; dt < 4; dt++) {
      bf16x4 w0, w1;
#pragma unroll
      for (int r = 0; r < 4; r++) { w0[r] = (bf16_t)Ot0[dt][r]; w1[r] = (bf16_t)Ot1[dt][r]; }
      *(bf16x4*)&Ob[row0 * 64 + dt * 16 + lg * 4] = w0;
      *(bf16x4*)&Ob[row1 * 64 + dt * 16 + lg * 4] = w1;
    }
    if (lg == 0) {
      mpart[psl * 128 + row0] = mrow0;
      lpart[psl * 128 + row0] = lrow0;
      mpart[psl * 128 + row1] = mrow1;
      lpart[psl * 128 + row1] = lrow1;
    }
  }
}

// ---------------- combine partials for q2 >= 3 -------------------------------------
__global__ __launch_bounds__(256) void attn_combine(
    const bf16_t* __restrict__ Opart, const float* __restrict__ mpart,
    const float* __restrict__ lpart, bf16_t* __restrict__ O)
{
  const int q2 = 3 + (blockIdx.x >> 1);
  const int half = blockIdx.x & 1;
  const int bh = blockIdx.y;
  const int g = q2 / 3, ns = g + 1;
  const int sbase = 3 * g * (g + 1) / 2 + (q2 - 3 * g) * (g + 1) - 3;
  const int psl0 = bh * 48 + sbase;
  const int tid = threadIdx.x;
  const int q = tid >> 2, d0 = (tid & 3) * 16;
  const int row = half * 64 + q;

  float M = -1e30f;
  for (int s = 0; s < ns; s++) M = fmaxf(M, mpart[(psl0 + s) * 128 + row]);
  float L = 0.f;
  float acc[16];
#pragma unroll
  for (int j = 0; j < 16; j++) acc[j] = 0.f;
  for (int s = 0; s < ns; s++) {
    const float w = __builtin_exp2f(mpart[(psl0 + s) * 128 + row] - M);
    L += w * lpart[(psl0 + s) * 128 + row];
    const bf16_t* Ob = Opart + ((size_t)(psl0 + s) * 128 + row) * 64 + d0;
    bf16x8 o0 = *(const bf16x8*)Ob;
    bf16x8 o1 = *(const bf16x8*)(Ob + 8);
#pragma unroll
    for (int j = 0; j < 8; j++) { acc[j] += w * (float)o0[j]; acc[8 + j] += w * (float)o1[j]; }
  }
  const float inv = 1.f / L;
  const int b = bh >> 4, h = bh & 15;
  const int srow = q2 * 128 + row;
  bf16_t* out = O + ((size_t)(b * S_DIM + srow)) * E_DIM + h * DH_DIM + d0;
  bf16x8 w0, w1;
#pragma unroll
  for (int j = 0; j < 8; j++) { w0[j] = (bf16_t)(acc[j] * inv); w1[j] = (bf16_t)(acc[8 + j] * inv); }
  *(bf16x8*)out = w0;
  *(bf16x8*)(out + 8) = w1;
}

// ---------------- launcher ---------------------------------------------------------
extern "C" void kernel_launch(void* const* d_in, const int* in_sizes, int n_in,
                              void* d_out, int out_size, void* d_ws, size_t ws_size,
                              hipStream_t stream)
{
  const float* x    = (const float*)d_in[0];
  const float* ln1g = (const float*)d_in[1];
  const float* ln1b = (const float*)d_in[2];
  const float* Wq   = (const float*)d_in[3];
  const float* Wk   = (const float*)d_in[4];
  const float* Wv   = (const float*)d_in[5];
  const float* Wo   = (const float*)d_in[6];
  const float* bo   = (const float*)d_in[7];
  const float* ln2g = (const float*)d_in[8];
  const float* ln2b = (const float*)d_in[9];
  const float* W1   = (const float*)d_in[10];
  const float* b1   = (const float*)d_in[11];
  const float* W2   = (const float*)d_in[12];
  const float* b2   = (const float*)d_in[13];

  char* ws = (char*)d_ws;
  bf16_t* WqkvT = (bf16_t*)(ws + 0);          //  6.29 MB (dead after QKV)
  bf16_t* WoT   = (bf16_t*)(ws + 6291456);    //  2.10 MB (dead after O-proj)
  bf16_t* W1T   = (bf16_t*)(ws + 8388608);    //  8.39 MB (dead after FFN1)
  bf16_t* W2T   = (bf16_t*)(ws + 16777216);   //  8.39 MB
  bf16_t* h1    = (bf16_t*)(ws + 25165824);   //  8.39 MB (dead after QKV)
  bf16_t* qb    = (bf16_t*)(ws + 33554432);   //  8.39 MB (dead after attn)
  bf16_t* kb    = (bf16_t*)(ws + 41943040);   //  8.39 MB
  bf16_t* vb    = (bf16_t*)(ws + 50331648);   //  8.39 MB  [b,h,d,s] transposed
  bf16_t* attnb = (bf16_t*)(ws + 58720256);   //  8.39 MB (dead after O-proj)
  float*  xmid  = (float* )(ws + 67108864);   // 16.78 MB f32
  bf16_t* h2    = (bf16_t*)(ws + 83886080);   //  8.39 MB (dead after FFN1)
  bf16_t* ff1   = (bf16_t*)(ws + 25165824);   // 33.55 MB over h1/qb/kb/vb
  bf16_t* Opart = (bf16_t*)(ws + 67108864);   // 25.17 MB [32*48][128][64] (over xmid/h2)
  float*  mpart = (float* )(ws + 25165824);   //  0.79 MB (over h1, consumed pre-O-proj)
  float*  lpart = (float* )(ws + 25952256);   //  0.79 MB
  bf16_t* po0   = (bf16_t*)(ws + 25165824);   //  8.39 MB O-proj bf16 partial (over h1)
  bf16_t* po1   = (bf16_t*)(ws + 33554432);   //  8.39 MB (over qb, dead post-attn)
  bf16_t* pf0   = (bf16_t*)(ws + 0);          // FFN2 partials over dead regions
  bf16_t* pf1   = (bf16_t*)(ws + 8388608);
  bf16_t* pf2   = (bf16_t*)(ws + 58720256);
  bf16_t* pf3   = (bf16_t*)(ws + 83886080);

  pack_weights<<<3072, 256, 0, stream>>>(Wq, Wk, Wv, WqkvT, Wo, WoT, W1, W1T, W2, W2T);

  ln_kernel<<<4096, 256, 0, stream>>>(x, ln1g, ln1b, h1);
  // QKV: grid 32m x 24n; regions 8x12 (4 x 2 region grid)
  gemm128_kernel<EPI_QKV><<<dim3(32, 24, 1), 256, 0, stream>>>(
      h1, WqkvT, 4096, 3072, 1024, 1024, 8, 12, nullptr,
      nullptr, nullptr, qb, kb, vb);
  attn_kernel<<<dim3(51, 32), 256, 0, stream>>>(qb, kb, vb, attnb, Opart, mpart, lpart);
  attn_combine<<<dim3(26, 32), 256, 0, stream>>>(Opart, mpart, lpart, attnb);
  // O-proj: per z grid 32m x 8n; regions 8x4 (4 x 2)
  gemm128_kernel<EPI_PART_B16><<<dim3(32, 8, 2), 256, 0, stream>>>(
      attnb, WoT, 4096, 1024, 1024, 512, 8, 4, nullptr,
      nullptr, po0, po1, nullptr, nullptr);
  reduce2_ln<<<4096, 256, 0, stream>>>(po0, po1, bo, x, ln2g, ln2b, xmid, h2);
  // FFN1: grid 16m x 16n; regions 8x4 (2 x 4)
  gemm256_kernel<EPI_BIAS_RELU><<<dim3(16, 16, 1), 512, 0, stream>>>(
      h2, W1T, 4096, 4096, 1024, 1024, 8, 4, b1,
      nullptr, ff1, nullptr, nullptr, nullptr);
  // FFN2: per z grid 16m x 4n; regions 4x2 (4 x 2)
  gemm256_kernel<EPI_PART_B16><<<dim3(16, 4, 4), 512, 0, stream>>>(
      ff1, W2T, 4096, 1024, 4096, 1024, 4, 2, nullptr,
      nullptr, pf0, pf1, pf2, pf3);
  reduce4<<<4096, 256, 0, stream>>>(pf0, pf1, pf2, pf3, b2, xmid, (float*)d_out);

  (void)in_sizes; (void)n_in; (void)out_size; (void)ws_size;
}